// Round 1
// baseline (1112.096 us; speedup 1.0000x reference)
//
#include <hip/hip_runtime.h>
#include <hip/hip_bf16.h>
#include <stdint.h>

// Problem constants
#define B_ROWS   8192
#define CTX_REAL 5124     // 4096 state + 4 task + 1024 action
#define CTX_PAD  5184     // padded to multiple of 64 (81*64), pad cols zeroed

typedef unsigned short u16;
typedef __attribute__((ext_vector_type(8))) short short8;
typedef __attribute__((ext_vector_type(4))) float f32x4;

#define AS1 __attribute__((address_space(1)))
#define AS3 __attribute__((address_space(3)))

__device__ __forceinline__ u16 f2bf(float f) {
    union { float f; uint32_t u; } v; v.f = f;
    uint32_t u = v.u;
    uint32_t r = 0x7fffu + ((u >> 16) & 1u);   // round-to-nearest-even
    return (u16)((u + r) >> 16);
}

// ---------------------------------------------------------------------------
// ctx = bf16([state | task_indicator | action | zeros]) , [B_ROWS][CTX_PAD]
// Each thread writes one aligned pair (all region boundaries are even).
// ---------------------------------------------------------------------------
__global__ void build_ctx(const float* __restrict__ state,
                          const float* __restrict__ ti,
                          const float* __restrict__ action,
                          u16* __restrict__ ctx) {
    const int row = blockIdx.y;
    const int c2  = blockIdx.x * blockDim.x + threadIdx.x;
    const int col = c2 * 2;
    if (col >= CTX_PAD) return;

    float v0, v1;
    {
        int c = col;
        v0 = (c < 4096) ? state[(size_t)row * 4096 + c]
           : (c < 4100) ? ti[(size_t)row * 4 + (c - 4096)]
           : (c < 5124) ? action[(size_t)row * 1024 + (c - 4100)]
           : 0.0f;
        c = col + 1;
        v1 = (c < 4096) ? state[(size_t)row * 4096 + c]
           : (c < 4100) ? ti[(size_t)row * 4 + (c - 4096)]
           : (c < 5124) ? action[(size_t)row * 1024 + (c - 4100)]
           : 0.0f;
    }
    uint32_t packed = (uint32_t)f2bf(v0) | ((uint32_t)f2bf(v1) << 16);
    *(uint32_t*)&ctx[(size_t)row * CTX_PAD + col] = packed;
}

// ---------------------------------------------------------------------------
// Wt[n][k] = bf16(W[k][n]) for k < K_real, else 0.   W: [K_real][N] fp32,
// Wt: [N][Kpad] bf16.  64x64 LDS-tiled transpose, coalesced both sides.
// grid = (Kpad/64, N/64), block = 256
// ---------------------------------------------------------------------------
__global__ void wconv(const float* __restrict__ W, u16* __restrict__ Wt,
                      int K_real, int Kpad, int N) {
    __shared__ float tile[64][65];
    const int k0 = blockIdx.x * 64;
    const int n0 = blockIdx.y * 64;
    const int t  = threadIdx.x;
#pragma unroll
    for (int i = 0; i < 16; ++i) {
        int idx = i * 256 + t;
        int r = idx >> 6, c = idx & 63;       // r: k offset, c: n offset
        int k = k0 + r;
        tile[r][c] = (k < K_real) ? W[(size_t)k * N + n0 + c] : 0.0f;
    }
    __syncthreads();
#pragma unroll
    for (int i = 0; i < 16; ++i) {
        int idx = i * 256 + t;
        int rn = idx >> 6, ck = idx & 63;     // rn: n offset, ck: k offset
        Wt[(size_t)(n0 + rn) * Kpad + k0 + ck] = f2bf(tile[ck][rn]);
    }
}

// ---------------------------------------------------------------------------
// GEMM: C[m][n] = sum_k A[m][k] * Wt[n][k] + bias[n]
// A is split: cols [0,K1) from A1 (stride lda1), cols [K1,Ktot) from A2
// (stride lda2).  K1, K2 multiples of 64 so each BK=64 chunk has one source.
// 128x128 tile, BK=64, 4 waves of 4x4 mfma_f32_16x16x32_bf16 (m97 structure),
// global_load_lds width-16 staging.  M, N multiples of 128; Ktot mult of 64.
// ---------------------------------------------------------------------------
template <bool OUT_BF16>
__global__ __launch_bounds__(256)
void gemm_bias(const u16* __restrict__ A1, int lda1, int K1,
               const u16* __restrict__ A2, int lda2,
               const u16* __restrict__ Bt, int ldb, int Ktot,
               const float* __restrict__ bias,
               void* __restrict__ Cout, int ldc) {
    __shared__ u16 tA[128 * 64];
    __shared__ u16 tB[128 * 64];

    const int t    = threadIdx.x;
    const int wave = t >> 6;
    const int lane = t & 63;
    const int quad = lane >> 4;
    const int l16  = lane & 15;
    const int wr   = (wave >> 1) * 64;    // wave's row offset inside 128-tile
    const int wc   = (wave & 1) * 64;     // wave's col offset inside 128-tile
    const int rowBase = blockIdx.x * 128;
    const int colBase = blockIdx.y * 128;

    // staging mapping: thread t covers row (t>>3) (+32 per iter), 8 bf16 at col (t&7)*8
    const int srow = t >> 3;
    const int scol = (t & 7) * 8;

    const u16* gA1 = A1 + (size_t)(rowBase + srow) * lda1 + scol;
    const u16* gA2 = A2 ? (A2 + (size_t)(rowBase + srow) * lda2 + scol) : gA1;
    const u16* gB  = Bt + (size_t)(colBase + srow) * ldb + scol;

    // wave-uniform LDS staging bases (HW adds lane*16 bytes)
    char* ldsA = (char*)tA + wave * 1024;
    char* ldsB = (char*)tB + wave * 1024;

    f32x4 acc[4][4] = {};

    const int nKt = Ktot >> 6;
    for (int kt = 0; kt < nKt; ++kt) {
        const int k0 = kt << 6;
        const u16* srcA;
        int strideA;
        if (k0 < K1) { srcA = gA1 + k0;        strideA = lda1; }
        else         { srcA = gA2 + (k0 - K1); strideA = lda2; }
        const u16* srcB = gB + k0;

        __syncthreads();   // previous tile fully consumed
#pragma unroll
        for (int it = 0; it < 4; ++it) {
            __builtin_amdgcn_global_load_lds(
                (AS1 const void*)(srcA + (size_t)(it * 32) * strideA),
                (AS3 void*)(ldsA + it * 4096), 16, 0, 0);
            __builtin_amdgcn_global_load_lds(
                (AS1 const void*)(srcB + (size_t)(it * 32) * ldb),
                (AS3 void*)(ldsB + it * 4096), 16, 0, 0);
        }
        __syncthreads();   // staged (compiler drains vmcnt before barrier)

        const u16* tAw = tA + wr * 64;
        const u16* tBw = tB + wc * 64;
#pragma unroll
        for (int kk = 0; kk < 2; ++kk) {
            const int kof = kk * 32 + quad * 8;
            short8 a[4], b[4];
#pragma unroll
            for (int i = 0; i < 4; ++i)
                a[i] = *(const short8*)(tAw + (i * 16 + l16) * 64 + kof);
#pragma unroll
            for (int j = 0; j < 4; ++j)
                b[j] = *(const short8*)(tBw + (j * 16 + l16) * 64 + kof);
#pragma unroll
            for (int i = 0; i < 4; ++i)
#pragma unroll
                for (int j = 0; j < 4; ++j)
                    acc[i][j] = __builtin_amdgcn_mfma_f32_16x16x32_bf16(
                        a[i], b[j], acc[i][j], 0, 0, 0);
        }
    }

    // epilogue: C/D layout col = lane&15, row = quad*4 + reg
    if (OUT_BF16) {
        u16* C = (u16*)Cout;
#pragma unroll
        for (int i = 0; i < 4; ++i) {
            const int r0 = rowBase + wr + i * 16 + quad * 4;
#pragma unroll
            for (int j = 0; j < 4; ++j) {
                const int c = colBase + wc + j * 16 + l16;
                const float bb = bias[c];
#pragma unroll
                for (int r = 0; r < 4; ++r)
                    C[(size_t)(r0 + r) * ldc + c] = f2bf(acc[i][j][r] + bb);
            }
        }
    } else {
        float* C = (float*)Cout;
#pragma unroll
        for (int i = 0; i < 4; ++i) {
            const int r0 = rowBase + wr + i * 16 + quad * 4;
#pragma unroll
            for (int j = 0; j < 4; ++j) {
                const int c = colBase + wc + j * 16 + l16;
                const float bb = bias[c];
#pragma unroll
                for (int r = 0; r < 4; ++r)
                    C[(size_t)(r0 + r) * ldc + c] = acc[i][j][r] + bb;
            }
        }
    }
}

// ---------------------------------------------------------------------------
extern "C" void kernel_launch(void* const* d_in, const int* in_sizes, int n_in,
                              void* d_out, int out_size, void* d_ws, size_t ws_size,
                              hipStream_t stream) {
    const float* state  = (const float*)d_in[0];
    const float* action = (const float*)d_in[1];
    const float* ti     = (const float*)d_in[2];
    // cx branches (d_in[3..18]) are dead wrt output — skipped.
    const float* W_l1 = (const float*)d_in[19]; const float* b_l1 = (const float*)d_in[20];
    const float* W_l2 = (const float*)d_in[21]; const float* b_l2 = (const float*)d_in[22];
    const float* W_l3 = (const float*)d_in[23]; const float* b_l3 = (const float*)d_in[24];
    const float* W_l4 = (const float*)d_in[25]; const float* b_l4 = (const float*)d_in[26];
    const float* W_l5 = (const float*)d_in[27]; const float* b_l5 = (const float*)d_in[28];

    char* ws = (char*)d_ws;
    size_t off = 0;
    auto alloc = [&](size_t bytes) -> void* {
        void* p = ws + off;
        off += (bytes + 255) & ~(size_t)255;
        return p;
    };
    u16* ctx = (u16*)alloc((size_t)B_ROWS * CTX_PAD * 2);
    u16* x1  = (u16*)alloc((size_t)B_ROWS * 2048 * 2);
    u16* x2  = (u16*)alloc((size_t)B_ROWS * 1024 * 2);
    u16* x3  = (u16*)alloc((size_t)B_ROWS * 1024 * 2);
    u16* x4  = (u16*)alloc((size_t)B_ROWS * 512 * 2);
    u16* W1t = (u16*)alloc((size_t)2048 * 5184 * 2);
    u16* W2t = (u16*)alloc((size_t)1024 * 7232 * 2);
    u16* W3t = (u16*)alloc((size_t)1024 * 6208 * 2);
    u16* W4t = (u16*)alloc((size_t)512  * 6208 * 2);
    u16* W5t = (u16*)alloc((size_t)1024 * 512  * 2);

    // Stage 1: bf16 conversions (ctx assembly + weight transposes)
    build_ctx<<<dim3((CTX_PAD / 2 + 255) / 256, B_ROWS), 256, 0, stream>>>(state, ti, action, ctx);
    wconv<<<dim3(81, 32),  256, 0, stream>>>(W_l1, W1t, 5124, 5184, 2048);
    wconv<<<dim3(113, 16), 256, 0, stream>>>(W_l2, W2t, 7172, 7232, 1024);
    wconv<<<dim3(97, 16),  256, 0, stream>>>(W_l3, W3t, 6148, 6208, 1024);
    wconv<<<dim3(97, 8),   256, 0, stream>>>(W_l4, W4t, 6148, 6208, 512);
    wconv<<<dim3(8, 16),   256, 0, stream>>>(W_l5, W5t, 512, 512, 1024);

    // Stage 2: the live GEMM chain (concat folded in as split-K A sources)
    // L1: x1 = ctx @ W1 + b1           [8192,2048], K=5184
    gemm_bias<true><<<dim3(64, 16), 256, 0, stream>>>(
        ctx, CTX_PAD, CTX_PAD, nullptr, 0, W1t, 5184, 5184, b_l1, x1, 2048);
    // L2: x2 = [x1|ctx] @ W2 + b2     [8192,1024], K=2048+5184
    gemm_bias<true><<<dim3(64, 8), 256, 0, stream>>>(
        x1, 2048, 2048, ctx, CTX_PAD, W2t, 7232, 7232, b_l2, x2, 1024);
    // L3: x3 = [x2|ctx] @ W3 + b3     [8192,1024], K=1024+5184
    gemm_bias<true><<<dim3(64, 8), 256, 0, stream>>>(
        x2, 1024, 1024, ctx, CTX_PAD, W3t, 6208, 6208, b_l3, x3, 1024);
    // L4: x4 = [x3|ctx] @ W4 + b4     [8192,512],  K=1024+5184
    gemm_bias<true><<<dim3(64, 4), 256, 0, stream>>>(
        x3, 1024, 1024, ctx, CTX_PAD, W4t, 6208, 6208, b_l4, x4, 512);
    // L5: out = x4 @ W5 + b5 (fp32)   [8192,1024], K=512
    gemm_bias<false><<<dim3(64, 8), 256, 0, stream>>>(
        x4, 512, 512, nullptr, 0, W5t, 512, 512, b_l5, d_out, 1024);
}

// Round 2
// 985.804 us; speedup vs baseline: 1.1281x; 1.1281x over previous
//
#include <hip/hip_runtime.h>
#include <hip/hip_bf16.h>
#include <stdint.h>

// Problem constants
#define B_ROWS   8192
#define CTX_REAL 5124     // 4096 state + 4 task + 1024 action
#define CTX_PAD  5184     // padded to multiple of 64 (81*64), pad cols zeroed

typedef unsigned short u16;
typedef __attribute__((ext_vector_type(8))) short short8;
typedef __attribute__((ext_vector_type(4))) float f32x4;

#define AS1 __attribute__((address_space(1)))
#define AS3 __attribute__((address_space(3)))

__device__ __forceinline__ u16 f2bf(float f) {
    union { float f; uint32_t u; } v; v.f = f;
    uint32_t u = v.u;
    uint32_t r = 0x7fffu + ((u >> 16) & 1u);   // round-to-nearest-even
    return (u16)((u + r) >> 16);
}

// ---------------------------------------------------------------------------
// ctx = bf16([state | task_indicator | action | zeros]) , [B_ROWS][CTX_PAD]
// ---------------------------------------------------------------------------
__global__ void build_ctx(const float* __restrict__ state,
                          const float* __restrict__ ti,
                          const float* __restrict__ action,
                          u16* __restrict__ ctx) {
    const int row = blockIdx.y;
    const int c2  = blockIdx.x * blockDim.x + threadIdx.x;
    const int col = c2 * 2;
    if (col >= CTX_PAD) return;

    float v0, v1;
    {
        int c = col;
        v0 = (c < 4096) ? state[(size_t)row * 4096 + c]
           : (c < 4100) ? ti[(size_t)row * 4 + (c - 4096)]
           : (c < 5124) ? action[(size_t)row * 1024 + (c - 4100)]
           : 0.0f;
        c = col + 1;
        v1 = (c < 4096) ? state[(size_t)row * 4096 + c]
           : (c < 4100) ? ti[(size_t)row * 4 + (c - 4096)]
           : (c < 5124) ? action[(size_t)row * 1024 + (c - 4100)]
           : 0.0f;
    }
    uint32_t packed = (uint32_t)f2bf(v0) | ((uint32_t)f2bf(v1) << 16);
    *(uint32_t*)&ctx[(size_t)row * CTX_PAD + col] = packed;
}

// ---------------------------------------------------------------------------
// Wt[n][k] = bf16(W[k][n]) for k < K_real, else 0.   W: [K_real][N] fp32,
// Wt: [N][Kpad] bf16.  64x64 LDS-tiled transpose.
// ---------------------------------------------------------------------------
__global__ void wconv(const float* __restrict__ W, u16* __restrict__ Wt,
                      int K_real, int Kpad, int N) {
    __shared__ float tile[64][65];
    const int k0 = blockIdx.x * 64;
    const int n0 = blockIdx.y * 64;
    const int t  = threadIdx.x;
#pragma unroll
    for (int i = 0; i < 16; ++i) {
        int idx = i * 256 + t;
        int r = idx >> 6, c = idx & 63;       // r: k offset, c: n offset
        int k = k0 + r;
        tile[r][c] = (k < K_real) ? W[(size_t)k * N + n0 + c] : 0.0f;
    }
    __syncthreads();
#pragma unroll
    for (int i = 0; i < 16; ++i) {
        int idx = i * 256 + t;
        int rn = idx >> 6, ck = idx & 63;     // rn: n offset, ck: k offset
        Wt[(size_t)(n0 + rn) * Kpad + k0 + ck] = f2bf(tile[ck][rn]);
    }
}

// ---------------------------------------------------------------------------
// GEMM: C[m][n] = sum_k A[m][k] * Wt[n][k] + bias[n]
// A split-K across two sources (concat folded in); K1 multiple of 64.
// 128x128 tile, BK=64, 4 waves of 4x4 mfma_f32_16x16x32_bf16,
// global_load_lds width-16 staging with XOR chunk swizzle:
//   LDS slot (row, chunk c) holds global chunk (c ^ (row&7)), chunks = 16B.
// Staging lane->slot mapping is fixed by HW (base + lane*16B); we permute the
// SOURCE address instead.  Reads apply the same XOR -> each 16-lane phase
// covers all 32 banks (2-way = free) instead of 4 banks (16-way).
// ---------------------------------------------------------------------------
template <bool OUT_BF16>
__global__ __launch_bounds__(256)
void gemm_bias(const u16* __restrict__ A1, int lda1, int K1,
               const u16* __restrict__ A2, int lda2,
               const u16* __restrict__ Bt, int ldb, int Ktot,
               const float* __restrict__ bias,
               void* __restrict__ Cout, int ldc) {
    __shared__ u16 tA[128 * 64];
    __shared__ u16 tB[128 * 64];

    const int t    = threadIdx.x;
    const int wave = t >> 6;
    const int lane = t & 63;
    const int quad = lane >> 4;
    const int l16  = lane & 15;
    const int wr   = (wave >> 1) * 64;    // wave's row offset inside 128-tile
    const int wc   = (wave & 1) * 64;     // wave's col offset inside 128-tile
    const int rowBase = blockIdx.x * 128;
    const int colBase = blockIdx.y * 128;

    // staging mapping: thread t covers row (t>>3) (+32 per it iter),
    // 8 bf16 at swizzled chunk ((t&7) ^ (row&7)).  Row stride 32 keeps row&7.
    const int srow = t >> 3;
    const int scol = ((t & 7) ^ (srow & 7)) * 8;

    const u16* gA1 = A1 + (size_t)(rowBase + srow) * lda1 + scol;
    const u16* gA2 = A2 ? (A2 + (size_t)(rowBase + srow) * lda2 + scol) : gA1;
    const u16* gB  = Bt + (size_t)(colBase + srow) * ldb + scol;

    // wave-uniform LDS staging bases (HW adds lane*16 bytes)
    char* ldsA = (char*)tA + wave * 1024;
    char* ldsB = (char*)tB + wave * 1024;

    f32x4 acc[4][4] = {};

    const int nKt = Ktot >> 6;
    for (int kt = 0; kt < nKt; ++kt) {
        const int k0 = kt << 6;
        const u16* srcA;
        int strideA;
        if (k0 < K1) { srcA = gA1 + k0;        strideA = lda1; }
        else         { srcA = gA2 + (k0 - K1); strideA = lda2; }
        const u16* srcB = gB + k0;

        __syncthreads();   // previous tile fully consumed
#pragma unroll
        for (int it = 0; it < 4; ++it) {
            __builtin_amdgcn_global_load_lds(
                (AS1 const void*)(srcA + (size_t)(it * 32) * strideA),
                (AS3 void*)(ldsA + it * 4096), 16, 0, 0);
            __builtin_amdgcn_global_load_lds(
                (AS1 const void*)(srcB + (size_t)(it * 32) * ldb),
                (AS3 void*)(ldsB + it * 4096), 16, 0, 0);
        }
        __syncthreads();   // staged (compiler drains vmcnt before barrier)

        const u16* tAw = tA + wr * 64;
        const u16* tBw = tB + wc * 64;
#pragma unroll
        for (int kk = 0; kk < 2; ++kk) {
            // logical chunk index (16B units) within the 64-elem row
            const int kchunk = kk * 4 + quad;
            const int swz    = (kchunk ^ (l16 & 7)) * 8;   // element offset
            short8 a[4], b[4];
#pragma unroll
            for (int i = 0; i < 4; ++i)
                a[i] = *(const short8*)(tAw + (i * 16 + l16) * 64 + swz);
#pragma unroll
            for (int j = 0; j < 4; ++j)
                b[j] = *(const short8*)(tBw + (j * 16 + l16) * 64 + swz);
#pragma unroll
            for (int i = 0; i < 4; ++i)
#pragma unroll
                for (int j = 0; j < 4; ++j)
                    acc[i][j] = __builtin_amdgcn_mfma_f32_16x16x32_bf16(
                        a[i], b[j], acc[i][j], 0, 0, 0);
        }
    }

    // epilogue: C/D layout col = lane&15, row = quad*4 + reg
    if (OUT_BF16) {
        u16* C = (u16*)Cout;
#pragma unroll
        for (int i = 0; i < 4; ++i) {
            const int r0 = rowBase + wr + i * 16 + quad * 4;
#pragma unroll
            for (int j = 0; j < 4; ++j) {
                const int c = colBase + wc + j * 16 + l16;
                const float bb = bias[c];
#pragma unroll
                for (int r = 0; r < 4; ++r)
                    C[(size_t)(r0 + r) * ldc + c] = f2bf(acc[i][j][r] + bb);
            }
        }
    } else {
        float* C = (float*)Cout;
#pragma unroll
        for (int i = 0; i < 4; ++i) {
            const int r0 = rowBase + wr + i * 16 + quad * 4;
#pragma unroll
            for (int j = 0; j < 4; ++j) {
                const int c = colBase + wc + j * 16 + l16;
                const float bb = bias[c];
#pragma unroll
                for (int r = 0; r < 4; ++r)
                    C[(size_t)(r0 + r) * ldc + c] = acc[i][j][r] + bb;
            }
        }
    }
}

// ---------------------------------------------------------------------------
extern "C" void kernel_launch(void* const* d_in, const int* in_sizes, int n_in,
                              void* d_out, int out_size, void* d_ws, size_t ws_size,
                              hipStream_t stream) {
    const float* state  = (const float*)d_in[0];
    const float* action = (const float*)d_in[1];
    const float* ti     = (const float*)d_in[2];
    // cx branches (d_in[3..18]) are dead wrt output — skipped.
    const float* W_l1 = (const float*)d_in[19]; const float* b_l1 = (const float*)d_in[20];
    const float* W_l2 = (const float*)d_in[21]; const float* b_l2 = (const float*)d_in[22];
    const float* W_l3 = (const float*)d_in[23]; const float* b_l3 = (const float*)d_in[24];
    const float* W_l4 = (const float*)d_in[25]; const float* b_l4 = (const float*)d_in[26];
    const float* W_l5 = (const float*)d_in[27]; const float* b_l5 = (const float*)d_in[28];

    char* ws = (char*)d_ws;
    size_t off = 0;
    auto alloc = [&](size_t bytes) -> void* {
        void* p = ws + off;
        off += (bytes + 255) & ~(size_t)255;
        return p;
    };
    u16* ctx = (u16*)alloc((size_t)B_ROWS * CTX_PAD * 2);
    u16* x1  = (u16*)alloc((size_t)B_ROWS * 2048 * 2);
    u16* x2  = (u16*)alloc((size_t)B_ROWS * 1024 * 2);
    u16* x3  = (u16*)alloc((size_t)B_ROWS * 1024 * 2);
    u16* x4  = (u16*)alloc((size_t)B_ROWS * 512 * 2);
    u16* W1t = (u16*)alloc((size_t)2048 * 5184 * 2);
    u16* W2t = (u16*)alloc((size_t)1024 * 7232 * 2);
    u16* W3t = (u16*)alloc((size_t)1024 * 6208 * 2);
    u16* W4t = (u16*)alloc((size_t)512  * 6208 * 2);
    u16* W5t = (u16*)alloc((size_t)1024 * 512  * 2);

    // Stage 1: bf16 conversions (ctx assembly + weight transposes)
    build_ctx<<<dim3((CTX_PAD / 2 + 255) / 256, B_ROWS), 256, 0, stream>>>(state, ti, action, ctx);
    wconv<<<dim3(81, 32),  256, 0, stream>>>(W_l1, W1t, 5124, 5184, 2048);
    wconv<<<dim3(113, 16), 256, 0, stream>>>(W_l2, W2t, 7172, 7232, 1024);
    wconv<<<dim3(97, 16),  256, 0, stream>>>(W_l3, W3t, 6148, 6208, 1024);
    wconv<<<dim3(97, 8),   256, 0, stream>>>(W_l4, W4t, 6148, 6208, 512);
    wconv<<<dim3(8, 16),   256, 0, stream>>>(W_l5, W5t, 512, 512, 1024);

    // Stage 2: the live GEMM chain (concat folded in as split-K A sources)
    // L1: x1 = ctx @ W1 + b1           [8192,2048], K=5184
    gemm_bias<true><<<dim3(64, 16), 256, 0, stream>>>(
        ctx, CTX_PAD, CTX_PAD, nullptr, 0, W1t, 5184, 5184, b_l1, x1, 2048);
    // L2: x2 = [x1|ctx] @ W2 + b2     [8192,1024], K=2048+5184
    gemm_bias<true><<<dim3(64, 8), 256, 0, stream>>>(
        x1, 2048, 2048, ctx, CTX_PAD, W2t, 7232, 7232, b_l2, x2, 1024);
    // L3: x3 = [x2|ctx] @ W3 + b3     [8192,1024], K=1024+5184
    gemm_bias<true><<<dim3(64, 8), 256, 0, stream>>>(
        x2, 1024, 1024, ctx, CTX_PAD, W3t, 6208, 6208, b_l3, x3, 1024);
    // L4: x4 = [x3|ctx] @ W4 + b4     [8192,512],  K=1024+5184
    gemm_bias<true><<<dim3(64, 4), 256, 0, stream>>>(
        x3, 1024, 1024, ctx, CTX_PAD, W4t, 6208, 6208, b_l4, x4, 512);
    // L5: out = x4 @ W5 + b5 (fp32)   [8192,1024], K=512
    gemm_bias<false><<<dim3(64, 8), 256, 0, stream>>>(
        x4, 512, 512, nullptr, 0, W5t, 512, 512, b_l5, d_out, 1024);
}

// Round 3
// 975.588 us; speedup vs baseline: 1.1399x; 1.0105x over previous
//
#include <hip/hip_runtime.h>
#include <hip/hip_bf16.h>
#include <stdint.h>

// Problem constants
#define B_ROWS   8192
#define CTX_REAL 5124     // 4096 state + 4 task + 1024 action
#define CTX_PAD  5184     // padded to multiple of 64 (81*64), pad cols zeroed

typedef unsigned short u16;
typedef __attribute__((ext_vector_type(8))) short short8;
typedef __attribute__((ext_vector_type(4))) float f32x4;

#define AS1 __attribute__((address_space(1)))
#define AS3 __attribute__((address_space(3)))

__device__ __forceinline__ u16 f2bf(float f) {
    union { float f; uint32_t u; } v; v.f = f;
    uint32_t u = v.u;
    uint32_t r = 0x7fffu + ((u >> 16) & 1u);   // round-to-nearest-even
    return (u16)((u + r) >> 16);
}

// ---------------------------------------------------------------------------
// ctx = bf16([state | task_indicator | action | zeros]) , [B_ROWS][CTX_PAD]
// ---------------------------------------------------------------------------
__global__ void build_ctx(const float* __restrict__ state,
                          const float* __restrict__ ti,
                          const float* __restrict__ action,
                          u16* __restrict__ ctx) {
    const int row = blockIdx.y;
    const int c2  = blockIdx.x * blockDim.x + threadIdx.x;
    const int col = c2 * 2;
    if (col >= CTX_PAD) return;

    float v0, v1;
    {
        int c = col;
        v0 = (c < 4096) ? state[(size_t)row * 4096 + c]
           : (c < 4100) ? ti[(size_t)row * 4 + (c - 4096)]
           : (c < 5124) ? action[(size_t)row * 1024 + (c - 4100)]
           : 0.0f;
        c = col + 1;
        v1 = (c < 4096) ? state[(size_t)row * 4096 + c]
           : (c < 4100) ? ti[(size_t)row * 4 + (c - 4096)]
           : (c < 5124) ? action[(size_t)row * 1024 + (c - 4100)]
           : 0.0f;
    }
    uint32_t packed = (uint32_t)f2bf(v0) | ((uint32_t)f2bf(v1) << 16);
    *(uint32_t*)&ctx[(size_t)row * CTX_PAD + col] = packed;
}

// ---------------------------------------------------------------------------
// Wt[n][k] = bf16(W[k][n]) for k < K_real, else 0.   W: [K_real][N] fp32,
// Wt: [N][Kpad] bf16.  64x64 LDS-tiled transpose.
// ---------------------------------------------------------------------------
__global__ void wconv(const float* __restrict__ W, u16* __restrict__ Wt,
                      int K_real, int Kpad, int N) {
    __shared__ float tile[64][65];
    const int k0 = blockIdx.x * 64;
    const int n0 = blockIdx.y * 64;
    const int t  = threadIdx.x;
#pragma unroll
    for (int i = 0; i < 16; ++i) {
        int idx = i * 256 + t;
        int r = idx >> 6, c = idx & 63;       // r: k offset, c: n offset
        int k = k0 + r;
        tile[r][c] = (k < K_real) ? W[(size_t)k * N + n0 + c] : 0.0f;
    }
    __syncthreads();
#pragma unroll
    for (int i = 0; i < 16; ++i) {
        int idx = i * 256 + t;
        int rn = idx >> 6, ck = idx & 63;     // rn: n offset, ck: k offset
        Wt[(size_t)(n0 + rn) * Kpad + k0 + ck] = f2bf(tile[ck][rn]);
    }
}

// ---------------------------------------------------------------------------
// GEMM: C[m][n] = sum_k A[m][k] * Wt[n][k] + bias[n]
// A split-K across two sources (concat folded in); K1 multiple of 64.
// Block tile TM x TN, BK=64, 4 waves arranged MW x NW; per-wave frag tile
// FI x FJ of mfma_f32_16x16x32_bf16.  global_load_lds width-16 staging with
// XOR chunk swizzle (LDS slot (row,c) holds global chunk c^(row&7), 16B
// chunks) -> conflict-free ds_read_b128 (2-way max = free).
//   TM=256,TN=128,MW=4,NW=1: wave tile 64x128 (FI=4,FJ=8) — 25% fewer LDS
//   reads per MFMA than the 64x64 wave tile; LDS pipe drops below MFMA pipe.
//   TM=128,TN=128,MW=2,NW=2: the round-2 config, for small layers.
// ---------------------------------------------------------------------------
template <int TM, int TN, int MW, int NW, bool OUT_BF16>
__global__ __launch_bounds__(256, 2)
void gemm_bias(const u16* __restrict__ A1, int lda1, int K1,
               const u16* __restrict__ A2, int lda2,
               const u16* __restrict__ Bt, int ldb, int Ktot,
               const float* __restrict__ bias,
               void* __restrict__ Cout, int ldc) {
    constexpr int FI = TM / MW / 16;
    constexpr int FJ = TN / NW / 16;
    __shared__ u16 tA[TM * 64];
    __shared__ u16 tB[TN * 64];

    const int t    = threadIdx.x;
    const int wave = t >> 6;
    const int lane = t & 63;
    const int quad = lane >> 4;
    const int l16  = lane & 15;
    const int wr   = (wave / NW) * (TM / MW);   // wave row offset in tile
    const int wc   = (wave % NW) * (TN / NW);   // wave col offset in tile
    const int rowBase = blockIdx.x * TM;
    const int colBase = blockIdx.y * TN;

    // staging: thread t covers row (t>>3) (+32 per issue round),
    // 8 bf16 at swizzled chunk ((t&7) ^ (row&7)); 32 | row-step keeps row&7.
    const int srow = t >> 3;
    const int scol = ((t & 7) ^ (srow & 7)) * 8;

    const u16* gA1 = A1 + (size_t)(rowBase + srow) * lda1 + scol;
    const u16* gA2 = A2 ? (A2 + (size_t)(rowBase + srow) * lda2 + scol) : gA1;
    const u16* gB  = Bt + (size_t)(colBase + srow) * ldb + scol;

    // wave-uniform LDS staging bases (HW adds lane*16 bytes)
    char* ldsA = (char*)tA + wave * 1024;
    char* ldsB = (char*)tB + wave * 1024;

    f32x4 acc[FI][FJ] = {};

    const int nKt = Ktot >> 6;
    for (int kt = 0; kt < nKt; ++kt) {
        const int k0 = kt << 6;
        const u16* srcA;
        int strideA;
        if (k0 < K1) { srcA = gA1 + k0;        strideA = lda1; }
        else         { srcA = gA2 + (k0 - K1); strideA = lda2; }
        const u16* srcB = gB + k0;

        __syncthreads();   // previous tile fully consumed
#pragma unroll
        for (int it = 0; it < TM / 32; ++it)
            __builtin_amdgcn_global_load_lds(
                (AS1 const void*)(srcA + (size_t)(it * 32) * strideA),
                (AS3 void*)(ldsA + it * 4096), 16, 0, 0);
#pragma unroll
        for (int it = 0; it < TN / 32; ++it)
            __builtin_amdgcn_global_load_lds(
                (AS1 const void*)(srcB + (size_t)(it * 32) * ldb),
                (AS3 void*)(ldsB + it * 4096), 16, 0, 0);
        __syncthreads();   // staged (compiler drains vmcnt before barrier)

        const u16* tAw = tA + wr * 64;
        const u16* tBw = tB + wc * 64;
#pragma unroll
        for (int kk = 0; kk < 2; ++kk) {
            const int kchunk = kk * 4 + quad;              // 16B chunk index
            const int swz    = (kchunk ^ (l16 & 7)) * 8;   // element offset
            short8 a[FI], b[FJ];
#pragma unroll
            for (int i = 0; i < FI; ++i)
                a[i] = *(const short8*)(tAw + (i * 16 + l16) * 64 + swz);
#pragma unroll
            for (int j = 0; j < FJ; ++j)
                b[j] = *(const short8*)(tBw + (j * 16 + l16) * 64 + swz);
#pragma unroll
            for (int i = 0; i < FI; ++i)
#pragma unroll
                for (int j = 0; j < FJ; ++j)
                    acc[i][j] = __builtin_amdgcn_mfma_f32_16x16x32_bf16(
                        a[i], b[j], acc[i][j], 0, 0, 0);
        }
    }

    // epilogue: C/D layout col = lane&15, row = quad*4 + reg
    if (OUT_BF16) {
        u16* C = (u16*)Cout;
#pragma unroll
        for (int i = 0; i < FI; ++i) {
            const int r0 = rowBase + wr + i * 16 + quad * 4;
#pragma unroll
            for (int j = 0; j < FJ; ++j) {
                const int c = colBase + wc + j * 16 + l16;
                const float bb = bias[c];
#pragma unroll
                for (int r = 0; r < 4; ++r)
                    C[(size_t)(r0 + r) * ldc + c] = f2bf(acc[i][j][r] + bb);
            }
        }
    } else {
        float* C = (float*)Cout;
#pragma unroll
        for (int i = 0; i < FI; ++i) {
            const int r0 = rowBase + wr + i * 16 + quad * 4;
#pragma unroll
            for (int j = 0; j < FJ; ++j) {
                const int c = colBase + wc + j * 16 + l16;
                const float bb = bias[c];
#pragma unroll
                for (int r = 0; r < 4; ++r)
                    C[(size_t)(r0 + r) * ldc + c] = acc[i][j][r] + bb;
            }
        }
    }
}

// ---------------------------------------------------------------------------
extern "C" void kernel_launch(void* const* d_in, const int* in_sizes, int n_in,
                              void* d_out, int out_size, void* d_ws, size_t ws_size,
                              hipStream_t stream) {
    const float* state  = (const float*)d_in[0];
    const float* action = (const float*)d_in[1];
    const float* ti     = (const float*)d_in[2];
    // cx branches (d_in[3..18]) are dead wrt output — skipped.
    const float* W_l1 = (const float*)d_in[19]; const float* b_l1 = (const float*)d_in[20];
    const float* W_l2 = (const float*)d_in[21]; const float* b_l2 = (const float*)d_in[22];
    const float* W_l3 = (const float*)d_in[23]; const float* b_l3 = (const float*)d_in[24];
    const float* W_l4 = (const float*)d_in[25]; const float* b_l4 = (const float*)d_in[26];
    const float* W_l5 = (const float*)d_in[27]; const float* b_l5 = (const float*)d_in[28];

    char* ws = (char*)d_ws;
    size_t off = 0;
    auto alloc = [&](size_t bytes) -> void* {
        void* p = ws + off;
        off += (bytes + 255) & ~(size_t)255;
        return p;
    };
    u16* ctx = (u16*)alloc((size_t)B_ROWS * CTX_PAD * 2);
    u16* x1  = (u16*)alloc((size_t)B_ROWS * 2048 * 2);
    u16* x2  = (u16*)alloc((size_t)B_ROWS * 1024 * 2);
    u16* x3  = (u16*)alloc((size_t)B_ROWS * 1024 * 2);
    u16* x4  = (u16*)alloc((size_t)B_ROWS * 512 * 2);
    u16* W1t = (u16*)alloc((size_t)2048 * 5184 * 2);
    u16* W2t = (u16*)alloc((size_t)1024 * 7232 * 2);
    u16* W3t = (u16*)alloc((size_t)1024 * 6208 * 2);
    u16* W4t = (u16*)alloc((size_t)512  * 6208 * 2);
    u16* W5t = (u16*)alloc((size_t)1024 * 512  * 2);

    // Stage 1: bf16 conversions (ctx assembly + weight transposes)
    build_ctx<<<dim3((CTX_PAD / 2 + 255) / 256, B_ROWS), 256, 0, stream>>>(state, ti, action, ctx);
    wconv<<<dim3(81, 32),  256, 0, stream>>>(W_l1, W1t, 5124, 5184, 2048);
    wconv<<<dim3(113, 16), 256, 0, stream>>>(W_l2, W2t, 7172, 7232, 1024);
    wconv<<<dim3(97, 16),  256, 0, stream>>>(W_l3, W3t, 6148, 6208, 1024);
    wconv<<<dim3(97, 8),   256, 0, stream>>>(W_l4, W4t, 6148, 6208, 512);
    wconv<<<dim3(8, 16),   256, 0, stream>>>(W_l5, W5t, 512, 512, 1024);

    // Stage 2: the live GEMM chain (concat folded in as split-K A sources)
    // L1: x1 = ctx @ W1 + b1           [8192,2048], K=5184  (512 blocks)
    gemm_bias<256, 128, 4, 1, true><<<dim3(32, 16), 256, 0, stream>>>(
        ctx, CTX_PAD, CTX_PAD, nullptr, 0, W1t, 5184, 5184, b_l1, x1, 2048);
    // L2: x2 = [x1|ctx] @ W2 + b2     [8192,1024], K=2048+5184  (256 blocks)
    gemm_bias<256, 128, 4, 1, true><<<dim3(32, 8), 256, 0, stream>>>(
        x1, 2048, 2048, ctx, CTX_PAD, W2t, 7232, 7232, b_l2, x2, 1024);
    // L3: x3 = [x2|ctx] @ W3 + b3     [8192,1024], K=1024+5184  (256 blocks)
    gemm_bias<256, 128, 4, 1, true><<<dim3(32, 8), 256, 0, stream>>>(
        x2, 1024, 1024, ctx, CTX_PAD, W3t, 6208, 6208, b_l3, x3, 1024);
    // L4: x4 = [x3|ctx] @ W4 + b4     [8192,512],  K=1024+5184  (256 blocks)
    gemm_bias<128, 128, 2, 2, true><<<dim3(64, 4), 256, 0, stream>>>(
        x3, 1024, 1024, ctx, CTX_PAD, W4t, 6208, 6208, b_l4, x4, 512);
    // L5: out = x4 @ W5 + b5 (fp32)   [8192,1024], K=512  (512 blocks)
    gemm_bias<128, 128, 2, 2, false><<<dim3(64, 8), 256, 0, stream>>>(
        x4, 512, 512, nullptr, 0, W5t, 512, 512, b_l5, d_out, 1024);
}

// Round 4
// 944.642 us; speedup vs baseline: 1.1773x; 1.0328x over previous
//
#include <hip/hip_runtime.h>
#include <hip/hip_bf16.h>
#include <stdint.h>

// Problem constants
#define B_ROWS   8192
#define CTX_REAL 5124     // 4096 state + 4 task + 1024 action
#define CTX_PAD  5184     // padded to multiple of 64 (81*64), pad cols zeroed

typedef unsigned short u16;
typedef __attribute__((ext_vector_type(8))) short short8;
typedef __attribute__((ext_vector_type(16))) float f32x16;

#define AS1 __attribute__((address_space(1)))
#define AS3 __attribute__((address_space(3)))

__device__ __forceinline__ u16 f2bf(float f) {
    union { float f; uint32_t u; } v; v.f = f;
    uint32_t u = v.u;
    uint32_t r = 0x7fffu + ((u >> 16) & 1u);   // round-to-nearest-even
    return (u16)((u + r) >> 16);
}

// ---------------------------------------------------------------------------
// ctx = bf16([state | task_indicator | action | zeros]) , [B_ROWS][CTX_PAD]
// ---------------------------------------------------------------------------
__global__ void build_ctx(const float* __restrict__ state,
                          const float* __restrict__ ti,
                          const float* __restrict__ action,
                          u16* __restrict__ ctx) {
    const int row = blockIdx.y;
    const int c2  = blockIdx.x * blockDim.x + threadIdx.x;
    const int col = c2 * 2;
    if (col >= CTX_PAD) return;

    float v0, v1;
    {
        int c = col;
        v0 = (c < 4096) ? state[(size_t)row * 4096 + c]
           : (c < 4100) ? ti[(size_t)row * 4 + (c - 4096)]
           : (c < 5124) ? action[(size_t)row * 1024 + (c - 4100)]
           : 0.0f;
        c = col + 1;
        v1 = (c < 4096) ? state[(size_t)row * 4096 + c]
           : (c < 4100) ? ti[(size_t)row * 4 + (c - 4096)]
           : (c < 5124) ? action[(size_t)row * 1024 + (c - 4100)]
           : 0.0f;
    }
    uint32_t packed = (uint32_t)f2bf(v0) | ((uint32_t)f2bf(v1) << 16);
    *(uint32_t*)&ctx[(size_t)row * CTX_PAD + col] = packed;
}

// ---------------------------------------------------------------------------
// Wt[n][k] = bf16(W[k][n]) for k < K_real, else 0.   W: [K_real][N] fp32,
// Wt: [N][Kpad] bf16.  64x64 LDS-tiled transpose.
// ---------------------------------------------------------------------------
__global__ void wconv(const float* __restrict__ W, u16* __restrict__ Wt,
                      int K_real, int Kpad, int N) {
    __shared__ float tile[64][65];
    const int k0 = blockIdx.x * 64;
    const int n0 = blockIdx.y * 64;
    const int t  = threadIdx.x;
#pragma unroll
    for (int i = 0; i < 16; ++i) {
        int idx = i * 256 + t;
        int r = idx >> 6, c = idx & 63;       // r: k offset, c: n offset
        int k = k0 + r;
        tile[r][c] = (k < K_real) ? W[(size_t)k * N + n0 + c] : 0.0f;
    }
    __syncthreads();
#pragma unroll
    for (int i = 0; i < 16; ++i) {
        int idx = i * 256 + t;
        int rn = idx >> 6, ck = idx & 63;     // rn: n offset, ck: k offset
        Wt[(size_t)(n0 + rn) * Kpad + k0 + ck] = f2bf(tile[ck][rn]);
    }
}

// ---------------------------------------------------------------------------
// GEMM: C[m][n] = sum_k A[m][k] * Wt[n][k] + bias[n]
// A split-K across two sources (concat folded in); K1 multiple of 64.
// Block tile TM x TN, BK=64, 4 waves arranged MW x NW, per-wave frag tile
// FI x FJ of v_mfma_f32_32x32x16_bf16 (16 FLOP/LDS-byte vs 8 for 16x16x32 —
// halves LDS read pressure per MFMA; LDS pipe was the measured R3 cap).
// global_load_lds width-16 staging with XOR chunk swizzle (LDS slot (row,c)
// holds global chunk c^(row&7), 16B chunks) -> conflict-free ds_read_b128.
// Layouts (32x32x16): A/B: elem k = (lane>>5)*8 + j at row/col = lane&31;
// C/D: col = lane&31, row = (reg&3) + 8*(reg>>2) + 4*(lane>>5)  [m74/m101].
// ---------------------------------------------------------------------------
template <int TM, int TN, int MW, int NW, bool OUT_BF16>
__global__ __launch_bounds__(256, 2)
void gemm_bias(const u16* __restrict__ A1, int lda1, int K1,
               const u16* __restrict__ A2, int lda2,
               const u16* __restrict__ Bt, int ldb, int Ktot,
               const float* __restrict__ bias,
               void* __restrict__ Cout, int ldc) {
    constexpr int FI = TM / MW / 32;
    constexpr int FJ = TN / NW / 32;
    __shared__ u16 tA[TM * 64];
    __shared__ u16 tB[TN * 64];

    const int t    = threadIdx.x;
    const int wave = t >> 6;
    const int lane = t & 63;
    const int l32  = lane & 31;
    const int half = lane >> 5;
    const int lswz = lane & 7;                  // row&7 for fragment reads
    const int wr   = (wave / NW) * (TM / MW);   // wave row offset in tile
    const int wc   = (wave % NW) * (TN / NW);   // wave col offset in tile
    const int rowBase = blockIdx.x * TM;
    const int colBase = blockIdx.y * TN;

    // staging: thread t covers row (t>>3) (+32 per issue round),
    // 8 bf16 at swizzled chunk ((t&7) ^ (row&7)); 32 | row-step keeps row&7.
    const int srow = t >> 3;
    const int scol = ((t & 7) ^ (srow & 7)) * 8;

    const u16* gA1 = A1 + (size_t)(rowBase + srow) * lda1 + scol;
    const u16* gA2 = A2 ? (A2 + (size_t)(rowBase + srow) * lda2 + scol) : gA1;
    const u16* gB  = Bt + (size_t)(colBase + srow) * ldb + scol;

    // wave-uniform LDS staging bases (HW adds lane*16 bytes)
    char* ldsA = (char*)tA + wave * 1024;
    char* ldsB = (char*)tB + wave * 1024;

    f32x16 acc[FI][FJ] = {};

    const int nKt = Ktot >> 6;
    for (int kt = 0; kt < nKt; ++kt) {
        const int k0 = kt << 6;
        const u16* srcA;
        int strideA;
        if (k0 < K1) { srcA = gA1 + k0;        strideA = lda1; }
        else         { srcA = gA2 + (k0 - K1); strideA = lda2; }
        const u16* srcB = gB + k0;

        __syncthreads();   // previous tile fully consumed
#pragma unroll
        for (int it = 0; it < TM / 32; ++it)
            __builtin_amdgcn_global_load_lds(
                (AS1 const void*)(srcA + (size_t)(it * 32) * strideA),
                (AS3 void*)(ldsA + it * 4096), 16, 0, 0);
#pragma unroll
        for (int it = 0; it < TN / 32; ++it)
            __builtin_amdgcn_global_load_lds(
                (AS1 const void*)(srcB + (size_t)(it * 32) * ldb),
                (AS3 void*)(ldsB + it * 4096), 16, 0, 0);
        __syncthreads();   // staged (compiler drains vmcnt before barrier)

        const u16* tAw = tA + wr * 64;
        const u16* tBw = tB + wc * 64;
#pragma unroll
        for (int ks = 0; ks < 4; ++ks) {        // 4 k-steps of K=16
            const int kchunk = ks * 2 + half;              // 16B chunk index
            const int swz    = (kchunk ^ lswz) * 8;        // element offset
            short8 a[FI], b[FJ];
#pragma unroll
            for (int i = 0; i < FI; ++i)
                a[i] = *(const short8*)(tAw + (i * 32 + l32) * 64 + swz);
#pragma unroll
            for (int j = 0; j < FJ; ++j)
                b[j] = *(const short8*)(tBw + (j * 32 + l32) * 64 + swz);
#pragma unroll
            for (int i = 0; i < FI; ++i)
#pragma unroll
                for (int j = 0; j < FJ; ++j)
                    acc[i][j] = __builtin_amdgcn_mfma_f32_32x32x16_bf16(
                        a[i], b[j], acc[i][j], 0, 0, 0);
        }
    }

    // epilogue: C/D col = lane&31, row = (reg&3) + 8*(reg>>2) + 4*half
    if (OUT_BF16) {
        u16* C = (u16*)Cout;
#pragma unroll
        for (int i = 0; i < FI; ++i) {
            const int rbase = rowBase + wr + i * 32 + 4 * half;
#pragma unroll
            for (int j = 0; j < FJ; ++j) {
                const int c = colBase + wc + j * 32 + l32;
                const float bb = bias[c];
#pragma unroll
                for (int reg = 0; reg < 16; ++reg) {
                    const int r = rbase + (reg & 3) + 8 * (reg >> 2);
                    C[(size_t)r * ldc + c] = f2bf(acc[i][j][reg] + bb);
                }
            }
        }
    } else {
        float* C = (float*)Cout;
#pragma unroll
        for (int i = 0; i < FI; ++i) {
            const int rbase = rowBase + wr + i * 32 + 4 * half;
#pragma unroll
            for (int j = 0; j < FJ; ++j) {
                const int c = colBase + wc + j * 32 + l32;
                const float bb = bias[c];
#pragma unroll
                for (int reg = 0; reg < 16; ++reg) {
                    const int r = rbase + (reg & 3) + 8 * (reg >> 2);
                    C[(size_t)r * ldc + c] = acc[i][j][reg] + bb;
                }
            }
        }
    }
}

// ---------------------------------------------------------------------------
extern "C" void kernel_launch(void* const* d_in, const int* in_sizes, int n_in,
                              void* d_out, int out_size, void* d_ws, size_t ws_size,
                              hipStream_t stream) {
    const float* state  = (const float*)d_in[0];
    const float* action = (const float*)d_in[1];
    const float* ti     = (const float*)d_in[2];
    // cx branches (d_in[3..18]) are dead wrt output — skipped.
    const float* W_l1 = (const float*)d_in[19]; const float* b_l1 = (const float*)d_in[20];
    const float* W_l2 = (const float*)d_in[21]; const float* b_l2 = (const float*)d_in[22];
    const float* W_l3 = (const float*)d_in[23]; const float* b_l3 = (const float*)d_in[24];
    const float* W_l4 = (const float*)d_in[25]; const float* b_l4 = (const float*)d_in[26];
    const float* W_l5 = (const float*)d_in[27]; const float* b_l5 = (const float*)d_in[28];

    char* ws = (char*)d_ws;
    size_t off = 0;
    auto alloc = [&](size_t bytes) -> void* {
        void* p = ws + off;
        off += (bytes + 255) & ~(size_t)255;
        return p;
    };
    u16* ctx = (u16*)alloc((size_t)B_ROWS * CTX_PAD * 2);
    u16* x1  = (u16*)alloc((size_t)B_ROWS * 2048 * 2);
    u16* x2  = (u16*)alloc((size_t)B_ROWS * 1024 * 2);
    u16* x3  = (u16*)alloc((size_t)B_ROWS * 1024 * 2);
    u16* x4  = (u16*)alloc((size_t)B_ROWS * 512 * 2);
    u16* W1t = (u16*)alloc((size_t)2048 * 5184 * 2);
    u16* W2t = (u16*)alloc((size_t)1024 * 7232 * 2);
    u16* W3t = (u16*)alloc((size_t)1024 * 6208 * 2);
    u16* W4t = (u16*)alloc((size_t)512  * 6208 * 2);
    u16* W5t = (u16*)alloc((size_t)1024 * 512  * 2);

    // Stage 1: bf16 conversions (ctx assembly + weight transposes)
    build_ctx<<<dim3((CTX_PAD / 2 + 255) / 256, B_ROWS), 256, 0, stream>>>(state, ti, action, ctx);
    wconv<<<dim3(81, 32),  256, 0, stream>>>(W_l1, W1t, 5124, 5184, 2048);
    wconv<<<dim3(113, 16), 256, 0, stream>>>(W_l2, W2t, 7172, 7232, 1024);
    wconv<<<dim3(97, 16),  256, 0, stream>>>(W_l3, W3t, 6148, 6208, 1024);
    wconv<<<dim3(97, 8),   256, 0, stream>>>(W_l4, W4t, 6148, 6208, 512);
    wconv<<<dim3(8, 16),   256, 0, stream>>>(W_l5, W5t, 512, 512, 1024);

    // Stage 2: the live GEMM chain (concat folded in as split-K A sources)
    // L1: x1 = ctx @ W1 + b1           [8192,2048], K=5184  (512 blocks, 2/CU)
    gemm_bias<256, 128, 4, 1, true><<<dim3(32, 16), 256, 0, stream>>>(
        ctx, CTX_PAD, CTX_PAD, nullptr, 0, W1t, 5184, 5184, b_l1, x1, 2048);
    // L2: x2 = [x1|ctx] @ W2 + b2     [8192,1024], K=7232  (512 blocks, 2/CU)
    gemm_bias<128, 128, 2, 2, true><<<dim3(64, 8), 256, 0, stream>>>(
        x1, 2048, 2048, ctx, CTX_PAD, W2t, 7232, 7232, b_l2, x2, 1024);
    // L3: x3 = [x2|ctx] @ W3 + b3     [8192,1024], K=6208  (512 blocks, 2/CU)
    gemm_bias<128, 128, 2, 2, true><<<dim3(64, 8), 256, 0, stream>>>(
        x2, 1024, 1024, ctx, CTX_PAD, W3t, 6208, 6208, b_l3, x3, 1024);
    // L4: x4 = [x3|ctx] @ W4 + b4     [8192,512],  K=6208  (256 blocks)
    gemm_bias<128, 128, 2, 2, true><<<dim3(64, 4), 256, 0, stream>>>(
        x3, 1024, 1024, ctx, CTX_PAD, W4t, 6208, 6208, b_l4, x4, 512);
    // L5: out = x4 @ W5 + b5 (fp32)   [8192,1024], K=512  (512 blocks)
    gemm_bias<128, 128, 2, 2, false><<<dim3(64, 8), 256, 0, stream>>>(
        x4, 512, 512, nullptr, 0, W5t, 512, 512, b_l5, d_out, 1024);
}